// Round 1
// baseline (324.498 us; speedup 1.0000x reference)
//
#include <hip/hip_runtime.h>
#include <math.h>

#define NBINS 4096

// loss = max(x,0) - x*t + log1p(exp(-|x|)); always >= 0, finite.
__device__ __forceinline__ float bce_loss(float x, float t, float e /*= exp(-|x|)*/) {
    return fmaxf(x, 0.f) - x * t + __logf(1.f + e);
}

__global__ __launch_bounds__(256) void pass1_kernel(
    const float* __restrict__ xg, const float* __restrict__ tg,
    unsigned* __restrict__ hist1, double* __restrict__ sums, int n)
{
    __shared__ unsigned lh[NBINS];
    for (int i = threadIdx.x; i < NBINS; i += 256) lh[i] = 0u;
    __syncthreads();

    double sp = 0.0, spt = 0.0, st = 0.0;
    int tid = blockIdx.x * 256 + threadIdx.x;
    int stride = gridDim.x * 256;
    int n4 = n >> 2;
    const float4* x4 = (const float4*)xg;
    const float4* t4 = (const float4*)tg;
    for (int i = tid; i < n4; i += stride) {
        float4 xv = x4[i];
        float4 tv = t4[i];
        float xs[4] = {xv.x, xv.y, xv.z, xv.w};
        float ts[4] = {tv.x, tv.y, tv.z, tv.w};
        #pragma unroll
        for (int c = 0; c < 4; ++c) {
            float x = xs[c], t = ts[c];
            float e = __expf(-fabsf(x));
            float l = bce_loss(x, t, e);
            float pp = (x >= 0.f) ? (1.f / (1.f + e)) : (e / (1.f + e));
            sp  += (double)pp;
            spt += (double)(pp * t);
            st  += (double)t;
            unsigned bits = __float_as_uint(l);
            atomicAdd(&lh[bits >> 20], 1u);
        }
    }
    // scalar tail (n not multiple of 4)
    for (int i = (n4 << 2) + tid; i < n; i += stride) {
        float x = xg[i], t = tg[i];
        float e = __expf(-fabsf(x));
        float l = bce_loss(x, t, e);
        float pp = (x >= 0.f) ? (1.f / (1.f + e)) : (e / (1.f + e));
        sp += (double)pp; spt += (double)(pp * t); st += (double)t;
        atomicAdd(&lh[__float_as_uint(l) >> 20], 1u);
    }
    __syncthreads();
    for (int i = threadIdx.x; i < NBINS; i += 256) {
        unsigned c = lh[i];
        if (c) atomicAdd(&hist1[i], c);
    }
    // wave64 reduction of dice sums, one atomic per wave
    #pragma unroll
    for (int off = 32; off; off >>= 1) {
        sp  += __shfl_down(sp,  off);
        spt += __shfl_down(spt, off);
        st  += __shfl_down(st,  off);
    }
    if ((threadIdx.x & 63) == 0) {
        atomicAdd(&sums[0], sp);
        atomicAdd(&sums[1], spt);
        atomicAdd(&sums[2], st);
    }
}

__global__ __launch_bounds__(64) void select1_kernel(
    const unsigned* __restrict__ hist1, unsigned* __restrict__ sel, unsigned k)
{
    int lane = threadIdx.x;                 // one wave, 64 lanes
    int base = lane << 6;                   // 64 bins per lane
    unsigned long long chunk = 0;
    for (int j = 0; j < 64; ++j) chunk += hist1[base + j];
    unsigned long long s = chunk;           // inclusive suffix sum across lanes
    #pragma unroll
    for (int off = 1; off < 64; off <<= 1) {
        unsigned long long v = __shfl_down(s, off);
        if (lane + off < 64) s += v;
    }
    unsigned long long c = s - chunk;       // count strictly above top bin of my chunk
    for (int j = 63; j >= 0; --j) {
        unsigned h = hist1[base + j];
        if (c < (unsigned long long)k && (unsigned long long)k <= c + h) {
            sel[0] = (unsigned)(base + j);  // b1
            sel[1] = (unsigned)c;           // count strictly above b1
        }
        c += h;
    }
}

__global__ __launch_bounds__(256) void pass2_kernel(
    const float* __restrict__ xg, const float* __restrict__ tg,
    const unsigned* __restrict__ sel, unsigned* __restrict__ hist2,
    double* __restrict__ sums, int n)
{
    __shared__ unsigned lh[NBINS];
    for (int i = threadIdx.x; i < NBINS; i += 256) lh[i] = 0u;
    __syncthreads();
    unsigned b1 = sel[0];

    double sgt = 0.0;
    int tid = blockIdx.x * 256 + threadIdx.x;
    int stride = gridDim.x * 256;
    int n4 = n >> 2;
    const float4* x4 = (const float4*)xg;
    const float4* t4 = (const float4*)tg;
    for (int i = tid; i < n4; i += stride) {
        float4 xv = x4[i];
        float4 tv = t4[i];
        float xs[4] = {xv.x, xv.y, xv.z, xv.w};
        float ts[4] = {tv.x, tv.y, tv.z, tv.w};
        #pragma unroll
        for (int c = 0; c < 4; ++c) {
            float x = xs[c], t = ts[c];
            float e = __expf(-fabsf(x));
            float l = bce_loss(x, t, e);
            unsigned bits = __float_as_uint(l);
            unsigned b = bits >> 20;
            if (b > b1) sgt += (double)l;
            else if (b == b1) atomicAdd(&lh[(bits >> 8) & 0xFFFu], 1u);
        }
    }
    for (int i = (n4 << 2) + tid; i < n; i += stride) {
        float x = xg[i], t = tg[i];
        float e = __expf(-fabsf(x));
        float l = bce_loss(x, t, e);
        unsigned bits = __float_as_uint(l);
        unsigned b = bits >> 20;
        if (b > b1) sgt += (double)l;
        else if (b == b1) atomicAdd(&lh[(bits >> 8) & 0xFFFu], 1u);
    }
    __syncthreads();
    for (int i = threadIdx.x; i < NBINS; i += 256) {
        unsigned c = lh[i];
        if (c) atomicAdd(&hist2[i], c);
    }
    #pragma unroll
    for (int off = 32; off; off >>= 1) sgt += __shfl_down(sgt, off);
    if ((threadIdx.x & 63) == 0) atomicAdd(&sums[3], sgt);
}

__global__ __launch_bounds__(64) void final_kernel(
    const unsigned* __restrict__ hist2, const unsigned* __restrict__ sel,
    const double* __restrict__ sums, float* __restrict__ out, unsigned k)
{
    int lane = threadIdx.x;
    unsigned b1 = sel[0];
    unsigned long long k2 = (unsigned long long)k - sel[1];  // >= 1 by construction
    int base = lane << 6;

    unsigned long long cchunk = 0;
    double wchunk = 0.0;
    for (int j = 0; j < 64; ++j) {
        unsigned h = hist2[base + j];
        float v = __uint_as_float((b1 << 20) | ((unsigned)(base + j) << 8));
        cchunk += h;
        wchunk += (double)h * (double)v;
    }
    unsigned long long cs = cchunk;
    double wsum = wchunk;
    #pragma unroll
    for (int off = 1; off < 64; off <<= 1) {
        unsigned long long cv = __shfl_down(cs, off);
        double wv = __shfl_down(wsum, off);
        if (lane + off < 64) { cs += cv; wsum += wv; }
    }
    unsigned long long c = cs - cchunk;
    double w = wsum - wchunk;
    for (int j = 63; j >= 0; --j) {
        unsigned h = hist2[base + j];
        float v = __uint_as_float((b1 << 20) | ((unsigned)(base + j) << 8));
        if (c < k2 && k2 <= c + h) {
            double sum_top = sums[3] + w + (double)(k2 - c) * (double)v;
            double bce = sum_top / (double)k;
            double I = sums[1];
            double U = sums[0] + sums[2];
            double dice = (2.0 * I + 1e-6) / (U + 1e-6);
            out[0] = (float)(bce + 0.5 * (1.0 - dice));
        }
        c += h;
        w += (double)h * (double)v;
    }
}

extern "C" void kernel_launch(void* const* d_in, const int* in_sizes, int n_in,
                              void* d_out, int out_size, void* d_ws, size_t ws_size,
                              hipStream_t stream)
{
    const float* x = (const float*)d_in[0];
    const float* t = (const float*)d_in[1];
    float* out = (float*)d_out;
    int n = in_sizes[0];
    int ki = (int)((double)n * 0.2);   // Python int() truncation semantics
    if (ki < 1) ki = 1;
    unsigned k = (unsigned)ki;

    unsigned char* ws = (unsigned char*)d_ws;
    unsigned* hist1 = (unsigned*)(ws);              // 4096 u32 = 16 KB
    unsigned* hist2 = (unsigned*)(ws + 16384);      // 4096 u32 = 16 KB
    double*   sums  = (double*)(ws + 32768);        // [sp, spt, st, sum_gt]
    unsigned* sel   = (unsigned*)(ws + 32768 + 32); // [b1, cnt_gt1]

    // ws is poisoned 0xAA before every launch — zero what we use.
    hipMemsetAsync(d_ws, 0, 32768 + 64, stream);

    const int grid = 1024;  // 4 blocks/CU, 16 KB LDS each
    pass1_kernel<<<grid, 256, 0, stream>>>(x, t, hist1, sums, n);
    select1_kernel<<<1, 64, 0, stream>>>(hist1, sel, k);
    pass2_kernel<<<grid, 256, 0, stream>>>(x, t, sel, hist2, sums, n);
    final_kernel<<<1, 64, 0, stream>>>(hist2, sel, sums, out, k);
}

// Round 2
// 198.909 us; speedup vs baseline: 1.6314x; 1.6314x over previous
//
#include <hip/hip_runtime.h>
#include <math.h>
#include <float.h>
#include <limits.h>

#define NB1 8192    // sample histogram bins: float bits >> 19 (sign+exp+4 mantissa)
#define NB2 4096    // fine linear histogram bins over the band
#define BATCH 8     // float4 per thread in main kernel (32 elements)

// loss = max(x,0) - x*t + log1p(exp(-|x|)) >= 0 ; p = sigmoid(x)
__device__ __forceinline__ void elem_f(float x, float t, float& l, float& p) {
    float e = __expf(-fabsf(x));
    l = fmaxf(x, 0.f) - x * t + __logf(1.f + e);
    float r = __builtin_amdgcn_rcpf(1.f + e);
    p = (x >= 0.f) ? r : e * r;
}

// ---------- k0: 1/16 sample -> coarse bit-histogram ----------
__global__ __launch_bounds__(256) void sample_kernel(
    const float4* __restrict__ x4, const float4* __restrict__ t4,
    unsigned* __restrict__ H1, int n4)
{
    __shared__ unsigned lh[NB1];   // 32 KB
    for (int i = threadIdx.x; i < NB1; i += 256) lh[i] = 0u;
    __syncthreads();
    int tid = blockIdx.x * 256 + threadIdx.x;
    int stride = gridDim.x * 256;
    int ns = (n4 + 15) >> 4;       // every 16th float4
    for (int i = tid; i < ns; i += stride) {
        float4 xv = x4[(size_t)i << 4];
        float4 tv = t4[(size_t)i << 4];
        float xs[4] = {xv.x, xv.y, xv.z, xv.w};
        float ts[4] = {tv.x, tv.y, tv.z, tv.w};
        #pragma unroll
        for (int c = 0; c < 4; ++c) {
            float l, p;
            elem_f(xs[c], ts[c], l, p);
            atomicAdd(&lh[__float_as_uint(l) >> 19], 1u);
        }
    }
    __syncthreads();
    for (int i = threadIdx.x; i < NB1; i += 256) {
        unsigned c = lh[i];
        if (c) atomicAdd(&H1[i], c);
    }
}

// ---------- k1: pick value band [vlo, vhi) containing the kth value ----------
__global__ __launch_bounds__(64) void band_kernel(
    const unsigned* __restrict__ H1, float* __restrict__ band,
    long long ks, long long M)
{
    int lane = threadIdx.x;
    int base = lane << 7;          // 128 bins per lane
    unsigned long long chunk = 0;
    for (int j = 0; j < 128; ++j) chunk += H1[base + j];
    unsigned long long s = chunk;  // inclusive suffix-scan across lanes
    #pragma unroll
    for (int off = 1; off < 64; off <<= 1) {
        unsigned long long v = __shfl_down(s, off);
        if (lane + off < 64) s += v;
    }
    unsigned long long above = s - chunk;   // strictly above my chunk

    int my_bhi = INT_MAX, my_blo = -1;
    unsigned long long c = above;           // S(b): samples strictly above bin b
    for (int j = 127; j >= 0; --j) {
        unsigned h = H1[base + j];
        if ((long long)(c + h) < ks - M) my_bhi = base + j;          // min b: count(>= bottom of b) < ks-M
        if ((long long)c > ks + M && my_blo < 0) my_blo = base + j;  // max b: count(> b) > ks+M
        c += h;
    }
    #pragma unroll
    for (int off = 32; off; off >>= 1) {
        int a = __shfl_down(my_bhi, off); my_bhi = min(my_bhi, a);
        int b = __shfl_down(my_blo, off); my_blo = max(my_blo, b);
    }
    if (lane == 0) {
        int bhi = (my_bhi == INT_MAX) ? (NB1 - 1) : my_bhi;
        int blo = my_blo;                   // may be -1
        float vhi = __uint_as_float((unsigned)bhi << 19);
        float vlo = (blo < 0) ? 0.f : __uint_as_float((unsigned)(blo + 1) << 19);
        if (!(vlo < vhi)) vlo = 0.f;
        band[0] = vlo;
        band[1] = vhi;
    }
}

// ---------- k2: single full pass ----------
__global__ __launch_bounds__(256) void main_kernel(
    const float* __restrict__ xg, const float* __restrict__ tg,
    const float* __restrict__ band, unsigned* __restrict__ hist2,
    double* __restrict__ sums, unsigned long long* __restrict__ cntg, int n, int n4)
{
    const float4* x4 = (const float4*)xg;
    const float4* t4 = (const float4*)tg;
    float vlo = band[0], vhi = band[1];
    float scale = (float)NB2 / (vhi - vlo);

    int t0 = blockIdx.x * (256 * BATCH) + threadIdx.x;
    float4 xv[BATCH], tv[BATCH];
    #pragma unroll
    for (int j = 0; j < BATCH; ++j) {       // issue all loads before use
        int idx = t0 + j * 256;
        if (idx < n4) { xv[j] = x4[idx]; tv[j] = t4[idx]; }
    }

    float sp = 0.f, spt = 0.f, st = 0.f, sgt = 0.f;
    unsigned cnt = 0;
    #pragma unroll
    for (int j = 0; j < BATCH; ++j) {
        int idx = t0 + j * 256;
        if (idx >= n4) continue;
        float xs[4] = {xv[j].x, xv[j].y, xv[j].z, xv[j].w};
        float ts[4] = {tv[j].x, tv[j].y, tv[j].z, tv[j].w};
        #pragma unroll
        for (int c = 0; c < 4; ++c) {
            float l, p;
            elem_f(xs[c], ts[c], l, p);
            sp += p; spt += p * ts[c]; st += ts[c];
            if (l >= vhi) { cnt++; sgt += l; }
            else if (l >= vlo) {
                int b = (int)((l - vlo) * scale);
                b = min(b, NB2 - 1);
                atomicAdd(&hist2[b], 1u);
            }
        }
    }

    // scalar tail (n % 4) — direct atomics, negligible
    int tail0 = n4 << 2;
    if (blockIdx.x == 0 && threadIdx.x < (n - tail0)) {
        float l, p;
        elem_f(xg[tail0 + threadIdx.x], tg[tail0 + threadIdx.x], l, p);
        atomicAdd(&sums[0], (double)p);
        atomicAdd(&sums[1], (double)(p * tg[tail0 + threadIdx.x]));
        atomicAdd(&sums[2], (double)tg[tail0 + threadIdx.x]);
        if (l >= vhi) { atomicAdd(cntg, 1ull); atomicAdd(&sums[3], (double)l); }
        else if (l >= vlo) {
            int b = min((int)((l - vlo) * scale), NB2 - 1);
            atomicAdd(&hist2[b], 1u);
        }
    }

    // wave -> block -> one set of global atomics per block
    #pragma unroll
    for (int off = 32; off; off >>= 1) {
        sp  += __shfl_down(sp,  off);
        spt += __shfl_down(spt, off);
        st  += __shfl_down(st,  off);
        sgt += __shfl_down(sgt, off);
        cnt += __shfl_down(cnt, off);
    }
    __shared__ float    rs[4][4];
    __shared__ unsigned rc[4];
    int w = threadIdx.x >> 6;
    if ((threadIdx.x & 63) == 0) {
        rs[w][0] = sp; rs[w][1] = spt; rs[w][2] = st; rs[w][3] = sgt; rc[w] = cnt;
    }
    __syncthreads();
    if (threadIdx.x == 0) {
        double a0 = 0, a1 = 0, a2 = 0, a3 = 0;
        unsigned long long c = 0;
        for (int i = 0; i < 4; ++i) {
            a0 += rs[i][0]; a1 += rs[i][1]; a2 += rs[i][2]; a3 += rs[i][3]; c += rc[i];
        }
        atomicAdd(&sums[0], a0);
        atomicAdd(&sums[1], a1);
        atomicAdd(&sums[2], a2);
        atomicAdd(&sums[3], a3);
        atomicAdd(cntg, c);
    }
}

// ---------- k3: resolve threshold bin, emit scalar ----------
__global__ __launch_bounds__(64) void final_kernel(
    const unsigned* __restrict__ hist2, const float* __restrict__ band,
    const double* __restrict__ sums, const unsigned long long* __restrict__ cntg,
    float* __restrict__ out, long long k)
{
    int lane = threadIdx.x;
    double vlo = (double)band[0], vhi = (double)band[1];
    double binw = (vhi - vlo) / NB2;
    long long k2 = k - (long long)cntg[0];  // needed from band

    int base = lane << 6;                   // 64 bins per lane
    unsigned long long cchunk = 0;
    double wchunk = 0.0;
    for (int j = 0; j < 64; ++j) {
        unsigned h = hist2[base + j];
        cchunk += h;
        wchunk += (double)h * (vlo + (base + j + 0.5) * binw);
    }
    unsigned long long cs = cchunk;
    double wsum = wchunk;
    #pragma unroll
    for (int off = 1; off < 64; off <<= 1) {
        unsigned long long cv = __shfl_down(cs, off);
        double wv = __shfl_down(wsum, off);
        if (lane + off < 64) { cs += cv; wsum += wv; }
    }
    unsigned long long total = __shfl(cs, 0);
    double wtotal = __shfl(wsum, 0);

    double I = sums[1], U = sums[0] + sums[2];
    double dice_part = 0.5 * (1.0 - (2.0 * I + 1e-6) / (U + 1e-6));

    if (k2 <= 0) {                           // all of top-k above band (unreachable w/ margins)
        if (lane == 0) out[0] = (float)(sums[3] / (double)k + dice_part);
        return;
    }
    if ((unsigned long long)k2 > total) {    // band too high (unreachable w/ margins)
        if (lane == 0) {
            double sum_top = sums[3] + wtotal + (double)(k2 - (long long)total) * vlo;
            out[0] = (float)(sum_top / (double)k + dice_part);
        }
        return;
    }
    unsigned long long c = cs - cchunk;      // count strictly above my chunk
    double w = wsum - wchunk;                // weighted sum strictly above my chunk
    for (int j = 63; j >= 0; --j) {
        unsigned h = hist2[base + j];
        double val = vlo + (base + j + 0.5) * binw;
        if (c < (unsigned long long)k2 && (unsigned long long)k2 <= c + h) {
            double sum_top = sums[3] + w + (double)((long long)k2 - (long long)c) * val;
            out[0] = (float)(sum_top / (double)k + dice_part);
        }
        c += h;
        w += (double)h * val;
    }
}

extern "C" void kernel_launch(void* const* d_in, const int* in_sizes, int n_in,
                              void* d_out, int out_size, void* d_ws, size_t ws_size,
                              hipStream_t stream)
{
    const float* x = (const float*)d_in[0];
    const float* t = (const float*)d_in[1];
    float* out = (float*)d_out;
    int n = in_sizes[0];
    int n4 = n >> 2;
    long long k = (long long)((double)n * 0.2);   // Python int() truncation
    if (k < 1) k = 1;

    // sample rank target + safety margin
    long long S = (long long)((n4 + 15) >> 4) * 4;
    long long ks = (long long)((double)k * (double)S / (double)n);
    long long M = 4096;   // ~13 sigma of sample-rank noise; band stays tiny vs n

    unsigned char* ws = (unsigned char*)d_ws;
    unsigned* H1    = (unsigned*)(ws);                        // 32 KB
    unsigned* hist2 = (unsigned*)(ws + 32768);                // 16 KB
    double*   sums  = (double*)(ws + 32768 + 16384);          // 4 doubles
    unsigned long long* cntg = (unsigned long long*)(ws + 32768 + 16384 + 32);
    float*    band  = (float*)(ws + 32768 + 16384 + 48);      // vlo, vhi

    hipMemsetAsync(d_ws, 0, 32768 + 16384 + 64, stream);

    sample_kernel<<<128, 256, 0, stream>>>((const float4*)x, (const float4*)t, H1, n4);
    band_kernel<<<1, 64, 0, stream>>>(H1, band, ks, M);
    int grid = (n4 + 256 * BATCH - 1) / (256 * BATCH);
    main_kernel<<<grid, 256, 0, stream>>>(x, t, band, hist2, sums, cntg, n, n4);
    final_kernel<<<1, 64, 0, stream>>>(hist2, band, sums, cntg, out, k);
}